// Round 5
// baseline (700.432 us; speedup 1.0000x reference)
//
#include <hip/hip_runtime.h>
#include <math.h>

#define HW 512
#define NPIX (HW*HW)            // 262144
#define NB 4
#define NCIN 55
#define OUTX_SIZE (NB*55*NPIX)  // 57671680

// ws layout (float/uint offsets)
#define WA_OFF 0          // 37632 uints: [3 g][7 cb][7 step][64 lane][4] f16x2
#define WSUM_OFF 37632    // 18
#define BTSUM_OFF 37650   // 1
#define S_OFF 37664       // 1200: [600][2]
#define TM_OFF 38864      // 600
#define SBM_OFF 39464     // 600

#define BY 16              // output rows per block
#define BX 32              // output cols per block
#define LROWS 28           // BY + 12 halo
#define LSTRIDE 49         // LDS row stride in 16B cells (bank-phase rotate)
#define CELLS (LROWS*LSTRIDE)   // 1372 real cells
#define NLD 22             // wave-loads of 64x16B covering 1408 >= 1372 cells
#define LDSC 1408          // staged cells per buffer
#define NSTEP 7            // K-steps per (g, cb): 28 tap slots (25 real)
#define NCB 7              // channel-blocks of 8 (56 slots, 55 real)

// prepacked X16: per batch b, scratch = out + (b*55)<<18 floats, layout
// [cb 7][py 524][px 528] cells of 16B (8 f16 channels); py=gy+6, px=gx+8.
#define PH 524
#define PW 528
#define CBBYTES (PH*PW*16)  // 4,426,752

#define PREP_WBLK 147       // 147*256 = 37632 weight elements
#define PPK_TOT (NB*7*PH*(PW/4))   // 1,936,704 prepack threads (4px each)

typedef _Float16 half2v __attribute__((ext_vector_type(2)));
typedef __attribute__((ext_vector_type(8))) _Float16 f16x8;
typedef __attribute__((ext_vector_type(4))) float f32x4;

__device__ __forceinline__ uint pack_f16x2(float a, float b) {
  return __builtin_bit_cast(uint, __builtin_amdgcn_cvt_pkrtz(a, b));
}

__device__ __forceinline__ void gload16(const void* g, void* l) {
  __builtin_amdgcn_global_load_lds(
      (const __attribute__((address_space(1))) void*)g,
      (__attribute__((address_space(3))) void*)l, 16, 0, 0);
}

// Fused weight-pack + input-prepack.
// Blocks [0,147): weight A-fragments for mfma_f32_16x16x32_f16 per (g,cb,step):
//   lane l holds A[row=l&15][k=(l>>4)*8+j]; row=oc slot, tap=step*4+(l>>4),
//   ch = cb*8+j. Also wsum/btsum and S zeroing.
// Blocks [147,...): x f32 -> padded f16 8-ch cells (4 px per thread).
__global__ __launch_bounds__(256) void prep_prepack_kernel(
    const float* __restrict__ x,
    const float* __restrict__ w1, const float* __restrict__ w2, const float* __restrict__ w3,
    const float* __restrict__ wt, const float* __restrict__ bt,
    float* __restrict__ ws, float* __restrict__ out)
{
  const int blk = blockIdx.x;
  const int tid = threadIdx.x;
  if (blk < PREP_WBLK) {
    const int e = blk * 256 + tid;     // < 37632
    uint* wp = (uint*)(ws + WA_OFF);
    int u = e & 3;
    int rest = e >> 2;
    int lane = rest & 63;
    int idx = rest >> 6;               // (g*7 + cb)*7 + step
    int step = idx % 7;
    int cbg = idx / 7;
    int cb = cbg % 7;
    int g = cbg / 7;
    int oc = lane & 15;
    int kg = lane >> 4;
    int tap = step * 4 + kg;
    int c = cb * 8 + 2 * u;
    const float* wsrc = (g == 0) ? w1 : (g == 1) ? w2 : w3;
    float lo = 0.f, hi = 0.f;
    if (oc < 6 && tap < 25) {
      if (c < NCIN)     lo = wsrc[(oc * NCIN + c) * 25 + tap];
      if (c + 1 < NCIN) hi = wsrc[(oc * NCIN + c + 1) * 25 + tap];
    }
    wp[e] = pack_f16x2(lo, hi);
    if (e < 1200) ws[S_OFF + e] = 0.f;
    if (blk == 0) {
      if (tid < 18) {
        float s = 0.f;
        for (int o = 0; o < 36; o++) s += wt[o * 18 + tid];
        ws[WSUM_OFF + tid] = s;
      }
      if (tid == 18) {
        float s = 0.f;
        for (int o = 0; o < 36; o++) s += bt[o];
        ws[BTSUM_OFF] = s;
      }
    }
    return;
  }
  const uint idx = (uint)(blk - PREP_WBLK) * 256u + (uint)tid;
  if (idx >= (uint)PPK_TOT) return;
  const uint pw4 = idx % 132u;
  const uint r1 = idx / 132u;
  const uint py = r1 % 524u;
  const uint r2 = r1 / 524u;
  const uint cb = r2 % 7u;
  const uint b  = r2 / 7u;
  const int gy = (int)py - 6;
  const int gx = (int)(pw4 << 2) - 8;   // multiple of 4 -> aligned float4
  const bool in = ((unsigned)gy < (unsigned)HW) && (gx >= 0) && (gx < HW);
  const int c0 = cb * 8;
  float4 f[8];
#pragma unroll
  for (int q = 0; q < 8; q++) {
    float4 fz; fz.x = fz.y = fz.z = fz.w = 0.f;
    f[q] = (in && (c0 + q < NCIN))
         ? *(const float4*)(x + (((size_t)(b * NCIN + c0 + q)) << 18)
                              + (size_t)gy * HW + gx)
         : fz;
  }
  const float* fp = (const float*)&f[0];
  char* dst = (char*)(out + ((size_t)(b * 55) << 18))
            + (size_t)cb * CBBYTES + ((size_t)py * PW + (pw4 << 2)) * 16;
#pragma unroll
  for (int p = 0; p < 4; p++) {
    uint4 u;
    u.x = pack_f16x2(fp[0 * 4 + p], fp[1 * 4 + p]);
    u.y = pack_f16x2(fp[2 * 4 + p], fp[3 * 4 + p]);
    u.z = pack_f16x2(fp[4 * 4 + p], fp[5 * 4 + p]);
    u.w = pack_f16x2(fp[6 * 4 + p], fp[7 * 4 + p]);
    *(uint4*)(dst + p * 16) = u;
  }
}

// Implicit-GEMM conv, cb-outer / g-inner, double-buffered async LDS staging,
// fused cell-sum binning (replaces the old cellsum kernel).
__global__ __launch_bounds__(256, 3) void conv_kernel(
    const uint* wA, const float* bias1, const float* bias2, const float* bias3,
    const int* __restrict__ row_seg, const int* __restrict__ col_seg,
    const float* __restrict__ wsum18, const float* __restrict__ wb18,
    float* __restrict__ S, float* out)
{
  __shared__ uint xs[2 * LDSC * 4];   // 45056 B
  __shared__ float bins[1200];        // [600 cells][st, sb]
  const int tid = threadIdx.x;
  const int lane = tid & 63;
  const int wv = tid >> 6;          // wave 0..3 -> rows wv*4 .. wv*4+3
  const int h0 = blockIdx.y * BY, w0 = blockIdx.x * BX;
  const int bz = blockIdx.z;
  const int col = lane & 15;        // B/D: pixel column within n-tile
  const int kg  = lane >> 4;        // k-group: tap = step*4+kg ; D row base kg*4

  const char* xb = (const char*)out + (((size_t)(bz * 55)) << 20);  // scratch X16
  const uint4* wA4 = (const uint4*)wA;

  for (int e = tid; e < 1200; e += 256) bins[e] = 0.f;

  // per-lane staging source offsets (<=6 wave-loads/wave)
  uint voff[6];
#pragma unroll
  for (int t = 0; t < 6; t++) {
    int ld = wv * 6 + t;
    int l = ld * 64 + lane;
    if (l > CELLS - 1) l = CELLS - 1;
    int row = l / LSTRIDE;
    int c = l - row * LSTRIDE;
    if (c > 47) c = 47;
    voff[t] = (uint)(((h0 + row) * PW) + (w0 + c)) * 16u;
  }

  // tap spatial shifts (dword offsets), per g and step; padded taps -> 0
  int so[3][7];
#pragma unroll
  for (int g = 0; g < 3; g++) {
#pragma unroll
    for (int s = 0; s < 7; s++) {
      int tap = s * 4 + kg;
      int dr = 0, dc = 0;
      if (tap < 25) { int q5 = tap / 5; dr = q5 - 2; dc = tap - q5 * 5 - 2; }
      so[g][s] = ((dr * LSTRIDE + dc) * (g + 1)) << 2;
    }
  }

  f32x4 acc[3][8];
#pragma unroll
  for (int g = 0; g < 3; g++)
#pragma unroll
    for (int nt = 0; nt < 8; nt++) acc[g][nt] = (f32x4){0.f, 0.f, 0.f, 0.f};

  // prologue: stage cb=0 into buffer 0
#pragma unroll
  for (int t = 0; t < 6; t++) {
    int ld = wv * 6 + t;
    if (ld < NLD) gload16(xb + voff[t], (char*)xs + ld * 1024);
  }
  __syncthreads();

  int cur = 0;
#pragma unroll 1
  for (int cb = 0; cb < NCB; cb++) {
    if (cb < NCB - 1) {
      const char* sb = xb + (size_t)(cb + 1) * CBBYTES;
      char* db = (char*)(xs + (cur ^ 1) * (LDSC * 4));
#pragma unroll
      for (int t = 0; t < 6; t++) {
        int ld = wv * 6 + t;
        if (ld < NLD) gload16(sb + voff[t], db + ld * 1024);
      }
    }
    const uint* xsb = xs + cur * (LDSC * 4);
#pragma unroll
    for (int g = 0; g < 3; g++) {
      const uint4* wp4 = wA4 + (size_t)((g * NCB + cb) * NSTEP) * 64 + lane;
      f16x8 af[7];
#pragma unroll
      for (int s = 0; s < 7; s++)
        af[s] = __builtin_bit_cast(f16x8, wp4[(size_t)s * 64]);
#pragma unroll
      for (int nt = 0; nt < 8; nt++) {
        const int bd = (((6 + (wv << 2) + (nt >> 1)) * LSTRIDE)
                       + (8 + ((nt & 1) << 4) + col)) << 2;
        f32x4 a = acc[g][nt];
#pragma unroll
        for (int s = 0; s < 7; s++) {
          uint4 tv = *(const uint4*)&xsb[bd + so[g][s]];
          a = __builtin_amdgcn_mfma_f32_16x16x32_f16(
                af[s], __builtin_bit_cast(f16x8, tv), a, 0, 0, 0);
        }
        acc[g][nt] = a;
      }
    }
    __syncthreads();   // drains staging vmcnt + barrier
    cur ^= 1;
  }

  // epilogue: D row (kg*4+r) = oc slot, col = pixel; fused st/sb binning
  float bsel[3][4], wsl[3][4], wbl[3][4];
#pragma unroll
  for (int g = 0; g < 3; g++) {
    const float* bp = (g == 0) ? bias1 : (g == 1) ? bias2 : bias3;
#pragma unroll
    for (int r = 0; r < 4; r++) {
      int slot = (kg << 2) + r;
      bsel[g][r] = (slot < 6) ? bp[slot] : 0.f;
      wsl[g][r]  = (slot < 6) ? wsum18[g * 6 + slot] : 0.f;
      wbl[g][r]  = (slot < 6) ? wb18[g * 6 + slot] : 0.f;
    }
  }
#pragma unroll
  for (int nt = 0; nt < 8; nt++) {
    const int y = h0 + (wv << 2) + (nt >> 1);
    const int xx = w0 + ((nt & 1) << 4) + col;
    const size_t pix = (size_t)y * HW + xx;
    float stv = 0.f, sbv = 0.f;
#pragma unroll
    for (int g = 0; g < 3; g++) {
#pragma unroll
      for (int r = 0; r < 4; r++) {
        int slot = (kg << 2) + r;
        if (slot < 6) {
          float v = fmaxf(acc[g][nt][r] + bsel[g][r], 0.f);
          int ch = 36 + g * 6 + slot;
          out[(((size_t)(bz * 55 + ch)) << 18) + pix] = v;
          stv = fmaf(wsl[g][r], v, stv);
          sbv = fmaf(wbl[g][r], v, sbv);
        }
      }
    }
    stv += __shfl_xor(stv, 16);
    stv += __shfl_xor(stv, 32);
    sbv += __shfl_xor(sbv, 16);
    sbv += __shfl_xor(sbv, 32);
    if (lane < 16) {
      int cell = row_seg[y] * 20 + col_seg[xx];
      atomicAdd(&bins[cell * 2], stv);
      atomicAdd(&bins[cell * 2 + 1], sbv);
    }
  }
  __syncthreads();
  for (int e = tid; e < 1200; e += 256) {
    float v = bins[e];
    if (v != 0.f) atomicAdd(&S[e], v);
  }
}

__global__ __launch_bounds__(1024) void finalize_kernel(
    const int* __restrict__ row_seg, const int* __restrict__ col_seg,
    const float* __restrict__ S, const float* __restrict__ btsum,
    const float* __restrict__ bb, float* __restrict__ tm,
    float* __restrict__ sbm, float* __restrict__ out)
{
  __shared__ int rowcnt[30], colcnt[20];
  const int t = threadIdx.x;
  if (t < 30) rowcnt[t] = 0;
  if (t >= 32 && t < 52) colcnt[t - 32] = 0;
  __syncthreads();
  if (t < 512) atomicAdd(&rowcnt[row_seg[t]], 1);
  else atomicAdd(&colcnt[col_seg[t - 512]], 1);
  __syncthreads();
  if (t < 600) {
    int r = t / 20, c = t - r * 20;
    float cnt = (float)(rowcnt[r] * colcnt[c]);
    float topm = S[2 * t] / (cnt * 144.f) + btsum[0] * (1.f / 36.f);
    float botm = S[2 * t + 1] / (cnt * 4.f) + bb[0];
    tm[t] = topm;
    float s = 1.f / (1.f + expf(-botm));
    sbm[t] = s;
#pragma unroll
    for (int b = 0; b < 4; b++) out[OUTX_SIZE + b * 600 + t] = s;
  }
}

__global__ __launch_bounds__(256) void fill_kernel(
    const int* __restrict__ row_seg, const int* __restrict__ col_seg,
    const float* __restrict__ tm, const float* __restrict__ sbm,
    float* __restrict__ out)
{
  const int idx = blockIdx.x * 256 + threadIdx.x;  // < 262144 (4 px / thread)
  const int b = idx >> 16;
  const int p4 = idx & 65535;
  const int h = p4 >> 7, w = (p4 & 127) << 2;
  const int rs = row_seg[h] * 20;
  float4 tmv, sbv;
  {
    int c0 = rs + col_seg[w + 0];
    int c1 = rs + col_seg[w + 1];
    int c2 = rs + col_seg[w + 2];
    int c3 = rs + col_seg[w + 3];
    tmv.x = tm[c0]; tmv.y = tm[c1]; tmv.z = tm[c2]; tmv.w = tm[c3];
    sbv.x = sbm[c0]; sbv.y = sbm[c1]; sbv.z = sbm[c2]; sbv.w = sbm[c3];
  }
  const size_t hw = (size_t)h * HW + w;
  float* base = out + (((size_t)(b * 55)) << 18) + hw;
#pragma unroll
  for (int ch = 0; ch < 36; ch++) *(float4*)(base + ((size_t)ch << 18)) = tmv;
  *(float4*)(base + ((size_t)54 << 18)) = sbv;
}

extern "C" void kernel_launch(void* const* d_in, const int* in_sizes, int n_in,
                              void* d_out, int out_size, void* d_ws, size_t ws_size,
                              hipStream_t stream) {
  const float* x       = (const float*)d_in[0];
  const int*   row_seg = (const int*)d_in[1];
  const int*   col_seg = (const int*)d_in[2];
  const float* w1 = (const float*)d_in[3];
  const float* b1 = (const float*)d_in[4];
  const float* w2 = (const float*)d_in[5];
  const float* b2 = (const float*)d_in[6];
  const float* w3 = (const float*)d_in[7];
  const float* b3 = (const float*)d_in[8];
  const float* wt = (const float*)d_in[9];
  const float* bt = (const float*)d_in[10];
  const float* wb = (const float*)d_in[11];
  const float* bb = (const float*)d_in[12];
  float* out = (float*)d_out;
  float* ws  = (float*)d_ws;

  const int ppk_blocks = PREP_WBLK + (PPK_TOT + 255) / 256;
  prep_prepack_kernel<<<ppk_blocks, 256, 0, stream>>>(x, w1, w2, w3, wt, bt,
                                                      ws, out);

  dim3 g1(HW / BX, HW / BY, NB);
  conv_kernel<<<g1, 256, 0, stream>>>((const uint*)(ws + WA_OFF),
                                      b1, b2, b3, row_seg, col_seg,
                                      ws + WSUM_OFF, wb, ws + S_OFF, out);

  finalize_kernel<<<1, 1024, 0, stream>>>(row_seg, col_seg, ws + S_OFF,
                                          ws + BTSUM_OFF, bb,
                                          ws + TM_OFF, ws + SBM_OFF, out);

  fill_kernel<<<NB * NPIX / 1024, 256, 0, stream>>>(row_seg, col_seg,
                                                    ws + TM_OFF, ws + SBM_OFF, out);
}

// Round 6
// 665.859 us; speedup vs baseline: 1.0519x; 1.0519x over previous
//
#include <hip/hip_runtime.h>
#include <math.h>

#define HW 512
#define NPIX (HW*HW)            // 262144
#define NB 4
#define NCIN 55
#define OUTX_SIZE (NB*55*NPIX)  // 57671680

// ws layout (float/uint offsets)
#define WA_OFF 0          // 37632 uints: [3 g][7 cb][7 step][64 lane][4] f16x2
#define WSUM_OFF 37632    // 18
#define BTSUM_OFF 37650   // 1
#define S_OFF 37664       // 1200: [600][2]
#define TM_OFF 38864      // 600
#define SBM_OFF 39464     // 600

#define BY 16              // output rows per block
#define BX 32              // output cols per block
#define LROWS 28           // BY + 12 halo
#define LSTRIDE 49         // LDS row stride in 16B cells (bank-phase rotate)
#define CELLS (LROWS*LSTRIDE)   // 1372 real cells
#define NLD 22             // wave-loads of 64x16B covering 1408 >= 1372 cells
#define LDSC 1408          // staged cells per buffer
#define NSTEP 7            // K-steps per (g, cb): 28 tap slots (25 real)
#define NCB 7              // channel-blocks of 8 (56 slots, 55 real)

// prepacked X16: per batch b, scratch = out + (b*55)<<18 floats, layout
// [cb 7][py 524][px 528] cells of 16B (8 f16 channels); py=gy+6, px=gx+8.
#define PH 524
#define PW 528
#define CBBYTES (PH*PW*16)  // 4,426,752

#define PREP_WBLK 147       // 147*256 = 37632 weight elements
#define PPK_TOT (NB*7*PH*(PW/4))   // 1,936,704 prepack threads (4px each)

typedef _Float16 half2v __attribute__((ext_vector_type(2)));
typedef __attribute__((ext_vector_type(8))) _Float16 f16x8;
typedef __attribute__((ext_vector_type(4))) float f32x4;

__device__ __forceinline__ uint pack_f16x2(float a, float b) {
  return __builtin_bit_cast(uint, __builtin_amdgcn_cvt_pkrtz(a, b));
}

__device__ __forceinline__ void gload16(const void* g, void* l) {
  __builtin_amdgcn_global_load_lds(
      (const __attribute__((address_space(1))) void*)g,
      (__attribute__((address_space(3))) void*)l, 16, 0, 0);
}

// Fused weight-pack + input-prepack.
// Blocks [0,147): weight A-fragments for mfma_f32_16x16x32_f16 per (g,cb,step):
//   lane l holds A[row=l&15][k=(l>>4)*8+j]; row=oc slot, tap=step*4+(l>>4),
//   ch = cb*8+j. Also wsum/btsum and S zeroing.
// Blocks [147,...): x f32 -> padded f16 8-ch cells (4 px per thread).
__global__ __launch_bounds__(256) void prep_prepack_kernel(
    const float* __restrict__ x,
    const float* __restrict__ w1, const float* __restrict__ w2, const float* __restrict__ w3,
    const float* __restrict__ wt, const float* __restrict__ bt,
    float* __restrict__ ws, float* __restrict__ out)
{
  const int blk = blockIdx.x;
  const int tid = threadIdx.x;
  if (blk < PREP_WBLK) {
    const int e = blk * 256 + tid;     // < 37632
    uint* wp = (uint*)(ws + WA_OFF);
    int u = e & 3;
    int rest = e >> 2;
    int lane = rest & 63;
    int idx = rest >> 6;               // (g*7 + cb)*7 + step
    int step = idx % 7;
    int cbg = idx / 7;
    int cb = cbg % 7;
    int g = cbg / 7;
    int oc = lane & 15;
    int kg = lane >> 4;
    int tap = step * 4 + kg;
    int c = cb * 8 + 2 * u;
    const float* wsrc = (g == 0) ? w1 : (g == 1) ? w2 : w3;
    float lo = 0.f, hi = 0.f;
    if (oc < 6 && tap < 25) {
      if (c < NCIN)     lo = wsrc[(oc * NCIN + c) * 25 + tap];
      if (c + 1 < NCIN) hi = wsrc[(oc * NCIN + c + 1) * 25 + tap];
    }
    wp[e] = pack_f16x2(lo, hi);
    if (e < 1200) ws[S_OFF + e] = 0.f;
    if (blk == 0) {
      if (tid < 18) {
        float s = 0.f;
        for (int o = 0; o < 36; o++) s += wt[o * 18 + tid];
        ws[WSUM_OFF + tid] = s;
      }
      if (tid == 18) {
        float s = 0.f;
        for (int o = 0; o < 36; o++) s += bt[o];
        ws[BTSUM_OFF] = s;
      }
    }
    return;
  }
  const uint idx = (uint)(blk - PREP_WBLK) * 256u + (uint)tid;
  if (idx >= (uint)PPK_TOT) return;
  const uint pw4 = idx % 132u;
  const uint r1 = idx / 132u;
  const uint py = r1 % 524u;
  const uint r2 = r1 / 524u;
  const uint cb = r2 % 7u;
  const uint b  = r2 / 7u;
  const int gy = (int)py - 6;
  const int gx = (int)(pw4 << 2) - 8;   // multiple of 4 -> aligned float4
  const bool in = ((unsigned)gy < (unsigned)HW) && (gx >= 0) && (gx < HW);
  const int c0 = cb * 8;
  float4 f[8];
#pragma unroll
  for (int q = 0; q < 8; q++) { f[q].x = f[q].y = f[q].z = f[q].w = 0.f; }
  if (in) {
    const float* bp = x + (((size_t)(b * NCIN + c0)) << 18)
                    + (size_t)gy * HW + gx;
    if (cb < 6u) {
#pragma unroll
      for (int q = 0; q < 8; q++) f[q] = *(const float4*)(bp + ((size_t)q << 18));
    } else {
#pragma unroll
      for (int q = 0; q < 7; q++) f[q] = *(const float4*)(bp + ((size_t)q << 18));
    }
  }
  const float* fp = (const float*)&f[0];
  char* dst = (char*)(out + ((size_t)(b * 55) << 18))
            + (size_t)cb * CBBYTES + ((size_t)py * PW + (pw4 << 2)) * 16;
#pragma unroll
  for (int p = 0; p < 4; p++) {
    uint4 u;
    u.x = pack_f16x2(fp[0 * 4 + p], fp[1 * 4 + p]);
    u.y = pack_f16x2(fp[2 * 4 + p], fp[3 * 4 + p]);
    u.z = pack_f16x2(fp[4 * 4 + p], fp[5 * 4 + p]);
    u.w = pack_f16x2(fp[6 * 4 + p], fp[7 * 4 + p]);
    *(uint4*)(dst + p * 16) = u;
  }
}

// Implicit-GEMM conv, cb-outer / g-inner, double-buffered async LDS staging,
// fused cell-sum binning (replaces the old cellsum kernel).
// __launch_bounds__(256,2): (256,3) forced VGPR 84 + scratch spills
// (WRITE_SIZE +43MB, conv 242->281us). 2 waves/EU floor -> ~108-140 VGPR,
// no spill; occupancy may still reach 3 blocks/CU (LDS allows it).
__global__ __launch_bounds__(256, 2) void conv_kernel(
    const uint* wA, const float* bias1, const float* bias2, const float* bias3,
    const int* __restrict__ row_seg, const int* __restrict__ col_seg,
    const float* __restrict__ wsum18, const float* __restrict__ wb18,
    float* __restrict__ S, float* out)
{
  __shared__ uint xs[2 * LDSC * 4];   // 45056 B
  __shared__ float bins[1200];        // [600 cells][st, sb]
  const int tid = threadIdx.x;
  const int lane = tid & 63;
  const int wv = tid >> 6;          // wave 0..3 -> rows wv*4 .. wv*4+3
  const int h0 = blockIdx.y * BY, w0 = blockIdx.x * BX;
  const int bz = blockIdx.z;
  const int col = lane & 15;        // B/D: pixel column within n-tile
  const int kg  = lane >> 4;        // k-group: tap = step*4+kg ; D row base kg*4

  const char* xb = (const char*)out + (((size_t)(bz * 55)) << 20);  // scratch X16
  const uint4* wA4 = (const uint4*)wA;

  for (int e = tid; e < 1200; e += 256) bins[e] = 0.f;

  // per-lane staging source offsets (<=6 wave-loads/wave)
  uint voff[6];
#pragma unroll
  for (int t = 0; t < 6; t++) {
    int ld = wv * 6 + t;
    int l = ld * 64 + lane;
    if (l > CELLS - 1) l = CELLS - 1;
    int row = l / LSTRIDE;
    int c = l - row * LSTRIDE;
    if (c > 47) c = 47;
    voff[t] = (uint)(((h0 + row) * PW) + (w0 + c)) * 16u;
  }

  // tap spatial shifts (dword offsets), per g and step; padded taps -> 0
  int so[3][7];
#pragma unroll
  for (int g = 0; g < 3; g++) {
#pragma unroll
    for (int s = 0; s < 7; s++) {
      int tap = s * 4 + kg;
      int dr = 0, dc = 0;
      if (tap < 25) { int q5 = tap / 5; dr = q5 - 2; dc = tap - q5 * 5 - 2; }
      so[g][s] = ((dr * LSTRIDE + dc) * (g + 1)) << 2;
    }
  }

  f32x4 acc[3][8];
#pragma unroll
  for (int g = 0; g < 3; g++)
#pragma unroll
    for (int nt = 0; nt < 8; nt++) acc[g][nt] = (f32x4){0.f, 0.f, 0.f, 0.f};

  // prologue: stage cb=0 into buffer 0
#pragma unroll
  for (int t = 0; t < 6; t++) {
    int ld = wv * 6 + t;
    if (ld < NLD) gload16(xb + voff[t], (char*)xs + ld * 1024);
  }
  __syncthreads();

  int cur = 0;
#pragma unroll 1
  for (int cb = 0; cb < NCB; cb++) {
    if (cb < NCB - 1) {
      const char* sb = xb + (size_t)(cb + 1) * CBBYTES;
      char* db = (char*)(xs + (cur ^ 1) * (LDSC * 4));
#pragma unroll
      for (int t = 0; t < 6; t++) {
        int ld = wv * 6 + t;
        if (ld < NLD) gload16(sb + voff[t], db + ld * 1024);
      }
    }
    const uint* xsb = xs + cur * (LDSC * 4);
#pragma unroll
    for (int g = 0; g < 3; g++) {
      const uint4* wp4 = wA4 + (size_t)((g * NCB + cb) * NSTEP) * 64 + lane;
      f16x8 af[7];
#pragma unroll
      for (int s = 0; s < 7; s++)
        af[s] = __builtin_bit_cast(f16x8, wp4[(size_t)s * 64]);
#pragma unroll
      for (int nt = 0; nt < 8; nt++) {
        const int bd = (((6 + (wv << 2) + (nt >> 1)) * LSTRIDE)
                       + (8 + ((nt & 1) << 4) + col)) << 2;
        f32x4 a = acc[g][nt];
#pragma unroll
        for (int s = 0; s < 7; s++) {
          uint4 tv = *(const uint4*)&xsb[bd + so[g][s]];
          a = __builtin_amdgcn_mfma_f32_16x16x32_f16(
                af[s], __builtin_bit_cast(f16x8, tv), a, 0, 0, 0);
        }
        acc[g][nt] = a;
      }
    }
    __syncthreads();   // drains staging vmcnt + barrier
    cur ^= 1;
  }

  // epilogue: D row (kg*4+r) = oc slot, col = pixel; fused st/sb binning
  float bsel[3][4], wsl[3][4], wbl[3][4];
#pragma unroll
  for (int g = 0; g < 3; g++) {
    const float* bp = (g == 0) ? bias1 : (g == 1) ? bias2 : bias3;
#pragma unroll
    for (int r = 0; r < 4; r++) {
      int slot = (kg << 2) + r;
      bsel[g][r] = (slot < 6) ? bp[slot] : 0.f;
      wsl[g][r]  = (slot < 6) ? wsum18[g * 6 + slot] : 0.f;
      wbl[g][r]  = (slot < 6) ? wb18[g * 6 + slot] : 0.f;
    }
  }
#pragma unroll
  for (int nt = 0; nt < 8; nt++) {
    const int y = h0 + (wv << 2) + (nt >> 1);
    const int xx = w0 + ((nt & 1) << 4) + col;
    const size_t pix = (size_t)y * HW + xx;
    float stv = 0.f, sbv = 0.f;
#pragma unroll
    for (int g = 0; g < 3; g++) {
#pragma unroll
      for (int r = 0; r < 4; r++) {
        int slot = (kg << 2) + r;
        if (slot < 6) {
          float v = fmaxf(acc[g][nt][r] + bsel[g][r], 0.f);
          int ch = 36 + g * 6 + slot;
          out[(((size_t)(bz * 55 + ch)) << 18) + pix] = v;
          stv = fmaf(wsl[g][r], v, stv);
          sbv = fmaf(wbl[g][r], v, sbv);
        }
      }
    }
    stv += __shfl_xor(stv, 16);
    stv += __shfl_xor(stv, 32);
    sbv += __shfl_xor(sbv, 16);
    sbv += __shfl_xor(sbv, 32);
    if (lane < 16) {
      int cell = row_seg[y] * 20 + col_seg[xx];
      atomicAdd(&bins[cell * 2], stv);
      atomicAdd(&bins[cell * 2 + 1], sbv);
    }
  }
  __syncthreads();
  for (int e = tid; e < 1200; e += 256) {
    float v = bins[e];
    if (v != 0.f) atomicAdd(&S[e], v);
  }
}

__global__ __launch_bounds__(1024) void finalize_kernel(
    const int* __restrict__ row_seg, const int* __restrict__ col_seg,
    const float* __restrict__ S, const float* __restrict__ btsum,
    const float* __restrict__ bb, float* __restrict__ tm,
    float* __restrict__ sbm, float* __restrict__ out)
{
  __shared__ int rowcnt[30], colcnt[20];
  const int t = threadIdx.x;
  if (t < 30) rowcnt[t] = 0;
  if (t >= 32 && t < 52) colcnt[t - 32] = 0;
  __syncthreads();
  if (t < 512) atomicAdd(&rowcnt[row_seg[t]], 1);
  else atomicAdd(&colcnt[col_seg[t - 512]], 1);
  __syncthreads();
  if (t < 600) {
    int r = t / 20, c = t - r * 20;
    float cnt = (float)(rowcnt[r] * colcnt[c]);
    float topm = S[2 * t] / (cnt * 144.f) + btsum[0] * (1.f / 36.f);
    float botm = S[2 * t + 1] / (cnt * 4.f) + bb[0];
    tm[t] = topm;
    float s = 1.f / (1.f + expf(-botm));
    sbm[t] = s;
#pragma unroll
    for (int b = 0; b < 4; b++) out[OUTX_SIZE + b * 600 + t] = s;
  }
}

__global__ __launch_bounds__(256) void fill_kernel(
    const int* __restrict__ row_seg, const int* __restrict__ col_seg,
    const float* __restrict__ tm, const float* __restrict__ sbm,
    float* __restrict__ out)
{
  const int idx = blockIdx.x * 256 + threadIdx.x;  // < 262144 (4 px / thread)
  const int b = idx >> 16;
  const int p4 = idx & 65535;
  const int h = p4 >> 7, w = (p4 & 127) << 2;
  const int rs = row_seg[h] * 20;
  float4 tmv, sbv;
  {
    int c0 = rs + col_seg[w + 0];
    int c1 = rs + col_seg[w + 1];
    int c2 = rs + col_seg[w + 2];
    int c3 = rs + col_seg[w + 3];
    tmv.x = tm[c0]; tmv.y = tm[c1]; tmv.z = tm[c2]; tmv.w = tm[c3];
    sbv.x = sbm[c0]; sbv.y = sbm[c1]; sbv.z = sbm[c2]; sbv.w = sbm[c3];
  }
  const size_t hw = (size_t)h * HW + w;
  float* base = out + (((size_t)(b * 55)) << 18) + hw;
#pragma unroll
  for (int ch = 0; ch < 36; ch++) *(float4*)(base + ((size_t)ch << 18)) = tmv;
  *(float4*)(base + ((size_t)54 << 18)) = sbv;
}

extern "C" void kernel_launch(void* const* d_in, const int* in_sizes, int n_in,
                              void* d_out, int out_size, void* d_ws, size_t ws_size,
                              hipStream_t stream) {
  const float* x       = (const float*)d_in[0];
  const int*   row_seg = (const int*)d_in[1];
  const int*   col_seg = (const int*)d_in[2];
  const float* w1 = (const float*)d_in[3];
  const float* b1 = (const float*)d_in[4];
  const float* w2 = (const float*)d_in[5];
  const float* b2 = (const float*)d_in[6];
  const float* w3 = (const float*)d_in[7];
  const float* b3 = (const float*)d_in[8];
  const float* wt = (const float*)d_in[9];
  const float* bt = (const float*)d_in[10];
  const float* wb = (const float*)d_in[11];
  const float* bb = (const float*)d_in[12];
  float* out = (float*)d_out;
  float* ws  = (float*)d_ws;

  const int ppk_blocks = PREP_WBLK + (PPK_TOT + 255) / 256;
  prep_prepack_kernel<<<ppk_blocks, 256, 0, stream>>>(x, w1, w2, w3, wt, bt,
                                                      ws, out);

  dim3 g1(HW / BX, HW / BY, NB);
  conv_kernel<<<g1, 256, 0, stream>>>((const uint*)(ws + WA_OFF),
                                      b1, b2, b3, row_seg, col_seg,
                                      ws + WSUM_OFF, wb, ws + S_OFF, out);

  finalize_kernel<<<1, 1024, 0, stream>>>(row_seg, col_seg, ws + S_OFF,
                                          ws + BTSUM_OFF, bb,
                                          ws + TM_OFF, ws + SBM_OFF, out);

  fill_kernel<<<NB * NPIX / 1024, 256, 0, stream>>>(row_seg, col_seg,
                                                    ws + TM_OFF, ws + SBM_OFF, out);
}

// Round 7
// 655.302 us; speedup vs baseline: 1.0689x; 1.0161x over previous
//
#include <hip/hip_runtime.h>
#include <math.h>

#define HW 512
#define NPIX (HW*HW)            // 262144
#define NB 4
#define NCIN 55
#define OUTX_SIZE (NB*55*NPIX)  // 57671680

// ws layout (float/uint offsets)
#define WA_OFF 0          // 37632 uints: [3 g][7 cb][7 step][64 lane][4] f16x2
#define WSUM_OFF 37632    // 18
#define BTSUM_OFF 37650   // 1
#define S_OFF 37664       // 1200: [600][2]
#define TM_OFF 38864      // 600
#define SBM_OFF 39464     // 600

#define BY 16              // output rows per block
#define BX 32              // output cols per block
#define LROWS 28           // BY + 12 halo
#define LSTRIDE 49         // LDS row stride in 16B cells (bank-phase rotate)
#define CELLS (LROWS*LSTRIDE)   // 1372 real cells
#define NLD 22             // wave-loads of 64x16B covering 1408 >= 1372 cells
#define LDSC 1408          // staged cells per buffer
#define NSTEP 7            // K-steps per (g, cb): 28 tap slots (25 real)
#define NCB 7              // channel-blocks of 8 (56 slots, 55 real)

// prepacked X16: per batch b, scratch = out + (b*55)<<18 floats, layout
// [cb 7][py 524][px 528] cells of 16B (8 f16 channels); py=gy+6, px=gx+8.
#define PH 524
#define PW 528
#define CBBYTES (PH*PW*16)  // 4,426,752

#define PREP_WBLK 147       // 147*256 = 37632 weight elements
#define PPK_TOT (NB*7*PH*(PW/8))   // 968,352 prepack threads (8px each)

typedef _Float16 half2v __attribute__((ext_vector_type(2)));
typedef __attribute__((ext_vector_type(8))) _Float16 f16x8;
typedef __attribute__((ext_vector_type(4))) float f32x4;

__device__ __forceinline__ uint pack_f16x2(float a, float b) {
  return __builtin_bit_cast(uint, __builtin_amdgcn_cvt_pkrtz(a, b));
}

__device__ __forceinline__ void gload16(const void* g, void* l) {
  __builtin_amdgcn_global_load_lds(
      (const __attribute__((address_space(1))) void*)g,
      (__attribute__((address_space(3))) void*)l, 16, 0, 0);
}

// Fused weight-pack + input-prepack.
// Blocks [0,147): weight A-fragments for mfma_f32_16x16x32_f16 per (g,cb,step):
//   lane l holds A[row=l&15][k=(l>>4)*8+j]; row=oc slot, tap=step*4+(l>>4),
//   ch = cb*8+j. Also wsum/btsum and S zeroing.
// Blocks [147,...): x f32 -> padded f16 8-ch cells (8 px per thread; every
// thread's 8-px window is fully in-image or fully outside -> no partials).
__global__ __launch_bounds__(256) void prep_prepack_kernel(
    const float* __restrict__ x,
    const float* __restrict__ w1, const float* __restrict__ w2, const float* __restrict__ w3,
    const float* __restrict__ wt, const float* __restrict__ bt,
    float* __restrict__ ws, float* __restrict__ out)
{
  const int blk = blockIdx.x;
  const int tid = threadIdx.x;
  if (blk < PREP_WBLK) {
    const int e = blk * 256 + tid;     // < 37632
    uint* wp = (uint*)(ws + WA_OFF);
    int u = e & 3;
    int rest = e >> 2;
    int lane = rest & 63;
    int idx = rest >> 6;               // (g*7 + cb)*7 + step
    int step = idx % 7;
    int cbg = idx / 7;
    int cb = cbg % 7;
    int g = cbg / 7;
    int oc = lane & 15;
    int kg = lane >> 4;
    int tap = step * 4 + kg;
    int c = cb * 8 + 2 * u;
    const float* wsrc = (g == 0) ? w1 : (g == 1) ? w2 : w3;
    float lo = 0.f, hi = 0.f;
    if (oc < 6 && tap < 25) {
      if (c < NCIN)     lo = wsrc[(oc * NCIN + c) * 25 + tap];
      if (c + 1 < NCIN) hi = wsrc[(oc * NCIN + c + 1) * 25 + tap];
    }
    wp[e] = pack_f16x2(lo, hi);
    if (e < 1200) ws[S_OFF + e] = 0.f;
    if (blk == 0) {
      if (tid < 18) {
        float s = 0.f;
        for (int o = 0; o < 36; o++) s += wt[o * 18 + tid];
        ws[WSUM_OFF + tid] = s;
      }
      if (tid == 18) {
        float s = 0.f;
        for (int o = 0; o < 36; o++) s += bt[o];
        ws[BTSUM_OFF] = s;
      }
    }
    return;
  }
  const uint idx = (uint)(blk - PREP_WBLK) * 256u + (uint)tid;
  if (idx >= (uint)PPK_TOT) return;
  const uint pw8 = idx % 66u;
  const uint r1 = idx / 66u;
  const uint py = r1 % 524u;
  const uint r2 = r1 / 524u;
  const uint cb = r2 % 7u;
  const uint b  = r2 / 7u;
  const int gy = (int)py - 6;
  const int gx = (int)(pw8 << 3) - 8;   // multiple of 8; window fully in or out
  const bool in = ((unsigned)gy < (unsigned)HW) && (gx >= 0) && (gx < HW);
  const int c0 = cb * 8;
  char* dst = (char*)(out + ((size_t)(b * 55) << 18))
            + (size_t)cb * CBBYTES + ((size_t)py * PW + (pw8 << 3)) * 16;
  if (!in) {
    uint4 z; z.x = z.y = z.z = z.w = 0u;
#pragma unroll
    for (int p = 0; p < 8; p++) *(uint4*)(dst + p * 16) = z;
    return;
  }
  const float* bp = x + (((size_t)(b * NCIN + c0)) << 18) + (size_t)gy * HW + gx;
  float4 f[8][2];
#pragma unroll
  for (int q = 0; q < 8; q++) {
    f[q][0].x = f[q][0].y = f[q][0].z = f[q][0].w = 0.f;
    f[q][1].x = f[q][1].y = f[q][1].z = f[q][1].w = 0.f;
  }
  if (cb < 6u) {
#pragma unroll
    for (int q = 0; q < 8; q++) {
      f[q][0] = *(const float4*)(bp + ((size_t)q << 18));
      f[q][1] = *(const float4*)(bp + ((size_t)q << 18) + 4);
    }
  } else {
#pragma unroll
    for (int q = 0; q < 7; q++) {
      f[q][0] = *(const float4*)(bp + ((size_t)q << 18));
      f[q][1] = *(const float4*)(bp + ((size_t)q << 18) + 4);
    }
  }
#pragma unroll
  for (int h = 0; h < 2; h++) {
    const float* fp = (const float*)&f[0][0];
#pragma unroll
    for (int p = 0; p < 4; p++) {
      uint4 u;
      u.x = pack_f16x2(((const float*)&f[0][h])[p], ((const float*)&f[1][h])[p]);
      u.y = pack_f16x2(((const float*)&f[2][h])[p], ((const float*)&f[3][h])[p]);
      u.z = pack_f16x2(((const float*)&f[4][h])[p], ((const float*)&f[5][h])[p]);
      u.w = pack_f16x2(((const float*)&f[6][h])[p], ((const float*)&f[7][h])[p]);
      *(uint4*)(dst + (h * 4 + p) * 16) = u;
    }
    (void)fp;
  }
}

// Implicit-GEMM conv, cb-outer / g-inner, double-buffered async LDS staging,
// fused cell-sum binning. wsum/wb/bias live in LDS (swb[54]) instead of
// per-thread arrays: the 36-float bsel/wsl/wbl arrays were spilling
// (~113 B/thread scratch stores = the +29MB WRITE_SIZE R5/R6 regression).
__global__ __launch_bounds__(256, 2) void conv_kernel(
    const uint* wA, const float* bias1, const float* bias2, const float* bias3,
    const int* __restrict__ row_seg, const int* __restrict__ col_seg,
    const float* __restrict__ wsum18, const float* __restrict__ wb18,
    float* __restrict__ S, float* out)
{
  __shared__ uint xs[2 * LDSC * 4];   // 45056 B
  __shared__ float bins[1200];        // [600 cells][st, sb]
  __shared__ float swb[54];           // [0,18) wsum, [18,36) wb, [36,54) bias
  const int tid = threadIdx.x;
  const int lane = tid & 63;
  const int wv = tid >> 6;          // wave 0..3 -> rows wv*4 .. wv*4+3
  const int h0 = blockIdx.y * BY, w0 = blockIdx.x * BX;
  const int bz = blockIdx.z;
  const int col = lane & 15;        // B/D: pixel column within n-tile
  const int kg  = lane >> 4;        // k-group: tap = step*4+kg ; D row base kg*4

  const char* xb = (const char*)out + (((size_t)(bz * 55)) << 20);  // scratch X16
  const uint4* wA4 = (const uint4*)wA;

  for (int e = tid; e < 1200; e += 256) bins[e] = 0.f;
  if (tid < 18) swb[tid] = wsum18[tid];
  else if (tid < 36) swb[tid] = wb18[tid - 18];
  else if (tid < 54) {
    int k = tid - 36;                // 0..17
    int g = k / 6, o = k - g * 6;
    const float* bp = (g == 0) ? bias1 : (g == 1) ? bias2 : bias3;
    swb[tid] = bp[o];
  }

  // per-lane staging source offsets (<=6 wave-loads/wave)
  uint voff[6];
#pragma unroll
  for (int t = 0; t < 6; t++) {
    int ld = wv * 6 + t;
    int l = ld * 64 + lane;
    if (l > CELLS - 1) l = CELLS - 1;
    int row = l / LSTRIDE;
    int c = l - row * LSTRIDE;
    if (c > 47) c = 47;
    voff[t] = (uint)(((h0 + row) * PW) + (w0 + c)) * 16u;
  }

  // tap spatial shifts (dword offsets), per g and step; padded taps -> 0
  int so[3][7];
#pragma unroll
  for (int g = 0; g < 3; g++) {
#pragma unroll
    for (int s = 0; s < 7; s++) {
      int tap = s * 4 + kg;
      int dr = 0, dc = 0;
      if (tap < 25) { int q5 = tap / 5; dr = q5 - 2; dc = tap - q5 * 5 - 2; }
      so[g][s] = ((dr * LSTRIDE + dc) * (g + 1)) << 2;
    }
  }

  f32x4 acc[3][8];
#pragma unroll
  for (int g = 0; g < 3; g++)
#pragma unroll
    for (int nt = 0; nt < 8; nt++) acc[g][nt] = (f32x4){0.f, 0.f, 0.f, 0.f};

  // prologue: stage cb=0 into buffer 0
#pragma unroll
  for (int t = 0; t < 6; t++) {
    int ld = wv * 6 + t;
    if (ld < NLD) gload16(xb + voff[t], (char*)xs + ld * 1024);
  }
  __syncthreads();

  int cur = 0;
#pragma unroll 1
  for (int cb = 0; cb < NCB; cb++) {
    if (cb < NCB - 1) {
      const char* sb = xb + (size_t)(cb + 1) * CBBYTES;
      char* db = (char*)(xs + (cur ^ 1) * (LDSC * 4));
#pragma unroll
      for (int t = 0; t < 6; t++) {
        int ld = wv * 6 + t;
        if (ld < NLD) gload16(sb + voff[t], db + ld * 1024);
      }
    }
    const uint* xsb = xs + cur * (LDSC * 4);
#pragma unroll
    for (int g = 0; g < 3; g++) {
      const uint4* wp4 = wA4 + (size_t)((g * NCB + cb) * NSTEP) * 64 + lane;
      f16x8 af[7];
#pragma unroll
      for (int s = 0; s < 7; s++)
        af[s] = __builtin_bit_cast(f16x8, wp4[(size_t)s * 64]);
#pragma unroll
      for (int nt = 0; nt < 8; nt++) {
        const int bd = (((6 + (wv << 2) + (nt >> 1)) * LSTRIDE)
                       + (8 + ((nt & 1) << 4) + col)) << 2;
        f32x4 a = acc[g][nt];
#pragma unroll
        for (int s = 0; s < 7; s++) {
          uint4 tv = *(const uint4*)&xsb[bd + so[g][s]];
          a = __builtin_amdgcn_mfma_f32_16x16x32_f16(
                af[s], __builtin_bit_cast(f16x8, tv), a, 0, 0, 0);
        }
        acc[g][nt] = a;
      }
    }
    __syncthreads();   // drains staging vmcnt + barrier
    cur ^= 1;
  }

  // epilogue: D row (kg*4+r) = oc slot, col = pixel; fused st/sb binning.
  // wsum/wb/bias read from LDS swb (<=4 distinct addrs/wave, ~broadcast).
#pragma unroll
  for (int nt = 0; nt < 8; nt++) {
    const int y = h0 + (wv << 2) + (nt >> 1);
    const int xx = w0 + ((nt & 1) << 4) + col;
    const size_t pix = (size_t)y * HW + xx;
    float stv = 0.f, sbv = 0.f;
#pragma unroll
    for (int g = 0; g < 3; g++) {
#pragma unroll
      for (int r = 0; r < 4; r++) {
        int slot = (kg << 2) + r;
        if (slot < 6) {
          int k18 = g * 6 + slot;
          float v = fmaxf(acc[g][nt][r] + swb[36 + k18], 0.f);
          out[(((size_t)(bz * 55 + 36 + k18)) << 18) + pix] = v;
          stv = fmaf(swb[k18], v, stv);
          sbv = fmaf(swb[18 + k18], v, sbv);
        }
      }
    }
    stv += __shfl_xor(stv, 16);
    stv += __shfl_xor(stv, 32);
    sbv += __shfl_xor(sbv, 16);
    sbv += __shfl_xor(sbv, 32);
    if (lane < 16) {
      int cell = row_seg[y] * 20 + col_seg[xx];
      atomicAdd(&bins[cell * 2], stv);
      atomicAdd(&bins[cell * 2 + 1], sbv);
    }
  }
  __syncthreads();
  for (int e = tid; e < 1200; e += 256) {
    float v = bins[e];
    if (v != 0.f) atomicAdd(&S[e], v);
  }
}

__global__ __launch_bounds__(1024) void finalize_kernel(
    const int* __restrict__ row_seg, const int* __restrict__ col_seg,
    const float* __restrict__ S, const float* __restrict__ btsum,
    const float* __restrict__ bb, float* __restrict__ tm,
    float* __restrict__ sbm, float* __restrict__ out)
{
  __shared__ int rowcnt[30], colcnt[20];
  const int t = threadIdx.x;
  if (t < 30) rowcnt[t] = 0;
  if (t >= 32 && t < 52) colcnt[t - 32] = 0;
  __syncthreads();
  if (t < 512) atomicAdd(&rowcnt[row_seg[t]], 1);
  else atomicAdd(&colcnt[col_seg[t - 512]], 1);
  __syncthreads();
  if (t < 600) {
    int r = t / 20, c = t - r * 20;
    float cnt = (float)(rowcnt[r] * colcnt[c]);
    float topm = S[2 * t] / (cnt * 144.f) + btsum[0] * (1.f / 36.f);
    float botm = S[2 * t + 1] / (cnt * 4.f) + bb[0];
    tm[t] = topm;
    float s = 1.f / (1.f + expf(-botm));
    sbm[t] = s;
#pragma unroll
    for (int b = 0; b < 4; b++) out[OUTX_SIZE + b * 600 + t] = s;
  }
}

__global__ __launch_bounds__(256) void fill_kernel(
    const int* __restrict__ row_seg, const int* __restrict__ col_seg,
    const float* __restrict__ tm, const float* __restrict__ sbm,
    float* __restrict__ out)
{
  const int idx = blockIdx.x * 256 + threadIdx.x;  // < 262144 (4 px / thread)
  const int b = idx >> 16;
  const int p4 = idx & 65535;
  const int h = p4 >> 7, w = (p4 & 127) << 2;
  const int rs = row_seg[h] * 20;
  float4 tmv, sbv;
  {
    int c0 = rs + col_seg[w + 0];
    int c1 = rs + col_seg[w + 1];
    int c2 = rs + col_seg[w + 2];
    int c3 = rs + col_seg[w + 3];
    tmv.x = tm[c0]; tmv.y = tm[c1]; tmv.z = tm[c2]; tmv.w = tm[c3];
    sbv.x = sbm[c0]; sbv.y = sbm[c1]; sbv.z = sbm[c2]; sbv.w = sbm[c3];
  }
  const size_t hw = (size_t)h * HW + w;
  float* base = out + (((size_t)(b * 55)) << 18) + hw;
#pragma unroll
  for (int ch = 0; ch < 36; ch++) *(float4*)(base + ((size_t)ch << 18)) = tmv;
  *(float4*)(base + ((size_t)54 << 18)) = sbv;
}

extern "C" void kernel_launch(void* const* d_in, const int* in_sizes, int n_in,
                              void* d_out, int out_size, void* d_ws, size_t ws_size,
                              hipStream_t stream) {
  const float* x       = (const float*)d_in[0];
  const int*   row_seg = (const int*)d_in[1];
  const int*   col_seg = (const int*)d_in[2];
  const float* w1 = (const float*)d_in[3];
  const float* b1 = (const float*)d_in[4];
  const float* w2 = (const float*)d_in[5];
  const float* b2 = (const float*)d_in[6];
  const float* w3 = (const float*)d_in[7];
  const float* b3 = (const float*)d_in[8];
  const float* wt = (const float*)d_in[9];
  const float* bt = (const float*)d_in[10];
  const float* wb = (const float*)d_in[11];
  const float* bb = (const float*)d_in[12];
  float* out = (float*)d_out;
  float* ws  = (float*)d_ws;

  const int ppk_blocks = PREP_WBLK + (PPK_TOT + 255) / 256;
  prep_prepack_kernel<<<ppk_blocks, 256, 0, stream>>>(x, w1, w2, w3, wt, bt,
                                                      ws, out);

  dim3 g1(HW / BX, HW / BY, NB);
  conv_kernel<<<g1, 256, 0, stream>>>((const uint*)(ws + WA_OFF),
                                      b1, b2, b3, row_seg, col_seg,
                                      ws + WSUM_OFF, wb, ws + S_OFF, out);

  finalize_kernel<<<1, 1024, 0, stream>>>(row_seg, col_seg, ws + S_OFF,
                                          ws + BTSUM_OFF, bb,
                                          ws + TM_OFF, ws + SBM_OFF, out);

  fill_kernel<<<NB * NPIX / 1024, 256, 0, stream>>>(row_seg, col_seg,
                                                    ws + TM_OFF, ws + SBM_OFF, out);
}

// Round 8
// 613.806 us; speedup vs baseline: 1.1411x; 1.0676x over previous
//
#include <hip/hip_runtime.h>
#include <math.h>

#define HW 512
#define NPIX (HW*HW)            // 262144
#define NB 4
#define NCIN 55
#define OUTX_SIZE (NB*55*NPIX)  // 57671680

// ws layout (float/uint offsets)
#define WA_OFF 0          // 37632 uints: [3 g][7 cb][7 step][64 lane][4] f16x2
#define WSUM_OFF 37632    // 18
#define BTSUM_OFF 37650   // 1
#define S_OFF 37664       // 1200: [600][2]
#define TM_OFF 38864      // 600
#define SBM_OFF 39464     // 600

#define BY 16              // output rows per block
#define BX 32              // output cols per block
#define LROWS 28           // BY + 12 halo
#define LSTRIDE 49         // LDS row stride in 16B cells (bank-phase rotate)
#define CELLS (LROWS*LSTRIDE)   // 1372 cells per buffer
#define NSLOT 336          // 28 rows x 12 col-quads staged per cb
#define NCB 7              // channel-blocks of 8 (56 slots, 55 real)

#define PREP_WBLK 147      // 147*256 = 37632 weight elements

typedef _Float16 half2v __attribute__((ext_vector_type(2)));
typedef __attribute__((ext_vector_type(8))) _Float16 f16x8;
typedef __attribute__((ext_vector_type(4))) float f32x4;

__device__ __forceinline__ uint pack_f16x2(float a, float b) {
  return __builtin_bit_cast(uint, __builtin_amdgcn_cvt_pkrtz(a, b));
}

// Weight A-fragments for mfma_f32_16x16x32_f16, per (g, cb, step):
// lane l holds A[row=l&15][k=(l>>4)*8+j]; row=oc slot, tap=step*4+(l>>4),
// ch = cb*8+j. Also wsum/btsum and S zeroing.
__global__ __launch_bounds__(256) void prep_kernel(
    const float* __restrict__ w1, const float* __restrict__ w2, const float* __restrict__ w3,
    const float* __restrict__ wt, const float* __restrict__ bt,
    float* __restrict__ ws)
{
  const int blk = blockIdx.x;
  const int tid = threadIdx.x;
  const int e = blk * 256 + tid;     // < 37632
  uint* wp = (uint*)(ws + WA_OFF);
  int u = e & 3;
  int rest = e >> 2;
  int lane = rest & 63;
  int idx = rest >> 6;               // (g*7 + cb)*7 + step
  int step = idx % 7;
  int cbg = idx / 7;
  int cb = cbg % 7;
  int g = cbg / 7;
  int oc = lane & 15;
  int kg = lane >> 4;
  int tap = step * 4 + kg;
  int c = cb * 8 + 2 * u;
  const float* wsrc = (g == 0) ? w1 : (g == 1) ? w2 : w3;
  float lo = 0.f, hi = 0.f;
  if (oc < 6 && tap < 25) {
    if (c < NCIN)     lo = wsrc[(oc * NCIN + c) * 25 + tap];
    if (c + 1 < NCIN) hi = wsrc[(oc * NCIN + c + 1) * 25 + tap];
  }
  wp[e] = pack_f16x2(lo, hi);
  if (e < 1200) ws[S_OFF + e] = 0.f;
  if (blk == 0) {
    if (tid < 18) {
      float s = 0.f;
      for (int o = 0; o < 36; o++) s += wt[o * 18 + tid];
      ws[WSUM_OFF + tid] = s;
    }
    if (tid == 18) {
      float s = 0.f;
      for (int o = 0; o < 36; o++) s += bt[o];
      ws[BTSUM_OFF] = s;
    }
  }
}

// Implicit-GEMM conv with FUSED input staging (no prepack pass):
// reads x f32 directly, converts to f16x2 cells in-register, ds_write_b128
// into the stride-49 LDS tile. Per cb, the 336 staging slots are split in
// 3 sets of 112; set g's loads are ISSUED before phase g's 56 MFMAs and
// WRITTEN (to the other LDS buffer) after them -> HBM latency hides under
// MFMA. Waves 2-3 do no staging (pure compute). Fused cell-sum binning.
__global__ __launch_bounds__(256, 2) void conv_kernel(
    const float* __restrict__ x, const uint* wA,
    const float* bias1, const float* bias2, const float* bias3,
    const int* __restrict__ row_seg, const int* __restrict__ col_seg,
    const float* __restrict__ wsum18, const float* __restrict__ wb18,
    float* __restrict__ S, float* out)
{
  __shared__ uint xs[2 * CELLS * 4];  // 43904 B (2 buffers x 1372 cells x 16B)
  __shared__ float bins[1200];        // [600 cells][st, sb]
  __shared__ float swb[54];           // [0,18) wsum, [18,36) wb, [36,54) bias
  const int tid = threadIdx.x;
  const int lane = tid & 63;
  const int wv = tid >> 6;          // wave 0..3 -> rows wv*4 .. wv*4+3
  const int h0 = blockIdx.y * BY, w0 = blockIdx.x * BX;
  const int bz = blockIdx.z;
  const int col = lane & 15;        // B/D: pixel column within n-tile
  const int kg  = lane >> 4;        // k-group: tap = step*4+kg ; D row base kg*4

  const float* xbase = x + ((size_t)(bz * NCIN) << 18);
  const uint4* wA4 = (const uint4*)wA;

  for (int e = tid; e < 1200; e += 256) bins[e] = 0.f;
  if (tid < 18) swb[tid] = wsum18[tid];
  else if (tid < 36) swb[tid] = wb18[tid - 18];
  else if (tid < 54) {
    int k = tid - 36;                // 0..17
    int g = k / 6, o = k - g * 6;
    const float* bp = (g == 0) ? bias1 : (g == 1) ? bias2 : bias3;
    swb[tid] = bp[o];
  }

  // tap spatial shift (dil=1) per step, dword offset; padded taps -> 0
  int bofs[7];
#pragma unroll
  for (int s = 0; s < 7; s++) {
    int tap = s * 4 + kg;
    int dr = 0, dc = 0;
    if (tap < 25) { int q5 = tap / 5; dr = q5 - 2; dc = tap - q5 * 5 - 2; }
    bofs[s] = (dr * LSTRIDE + dc) << 2;
  }

  f32x4 acc[3][8];
#pragma unroll
  for (int g = 0; g < 3; g++)
#pragma unroll
    for (int nt = 0; nt < 8; nt++) acc[g][nt] = (f32x4){0.f, 0.f, 0.f, 0.f};

  // prologue: stage cb=0 (channels 0..7) synchronously into buffer 0
  for (int e = tid; e < NSLOT; e += 256) {
    int srow = e / 12, scg = e - srow * 12;
    int sgy = h0 - 6 + srow, sgx = w0 - 8 + (scg << 2);
    bool sin = ((unsigned)sgy < (unsigned)HW) && ((unsigned)sgx < (unsigned)HW);
    float4 sr[8];
#pragma unroll
    for (int q = 0; q < 8; q++) { sr[q].x = sr[q].y = sr[q].z = sr[q].w = 0.f; }
    if (sin) {
      const float* sp = xbase + (size_t)sgy * HW + sgx;
#pragma unroll
      for (int q = 0; q < 8; q++) sr[q] = *(const float4*)(sp + ((size_t)q << 18));
    }
    int cd = (srow * LSTRIDE + (scg << 2)) << 2;
#pragma unroll
    for (int p = 0; p < 4; p++) {
      uint4 u;
      u.x = pack_f16x2(((const float*)&sr[0])[p], ((const float*)&sr[1])[p]);
      u.y = pack_f16x2(((const float*)&sr[2])[p], ((const float*)&sr[3])[p]);
      u.z = pack_f16x2(((const float*)&sr[4])[p], ((const float*)&sr[5])[p]);
      u.w = pack_f16x2(((const float*)&sr[6])[p], ((const float*)&sr[7])[p]);
      *(uint4*)&xs[cd + 4 * p] = u;
    }
  }
  __syncthreads();

  int cur = 0;
#pragma unroll 1
  for (int cb = 0; cb < NCB; cb++) {
    const uint* xsb = xs + cur * (CELLS * 4);
    const bool pf = (cb < NCB - 1) && (tid < 112);
    const int c0n = (cb + 1) * 8;
#pragma unroll
    for (int g = 0; g < 3; g++) {
      // issue prefetch loads for slot-set g (targets buffer cur^1)
      float4 sr[8];
      int srow = 0, scg = 0;
#pragma unroll
      for (int q = 0; q < 8; q++) { sr[q].x = sr[q].y = sr[q].z = sr[q].w = 0.f; }
      if (pf) {
        int slot = g * 112 + tid;
        srow = slot / 12; scg = slot - srow * 12;
        int sgy = h0 - 6 + srow, sgx = w0 - 8 + (scg << 2);
        if (((unsigned)sgy < (unsigned)HW) && ((unsigned)sgx < (unsigned)HW)) {
          const float* sp = xbase + ((size_t)c0n << 18) + (size_t)sgy * HW + sgx;
          if (cb < NCB - 2) {          // next cb has all 8 channels
#pragma unroll
            for (int q = 0; q < 8; q++)
              sr[q] = *(const float4*)(sp + ((size_t)q << 18));
          } else {                     // cb+1 == 6: channels 48..54 (7 valid)
#pragma unroll
            for (int q = 0; q < 7; q++)
              sr[q] = *(const float4*)(sp + ((size_t)q << 18));
          }
        }
      }

      // A fragments for this (g, cb)
      const uint4* wp4 = wA4 + (size_t)((g * NCB + cb) * 7) * 64 + lane;
      f16x8 af[7];
#pragma unroll
      for (int s = 0; s < 7; s++)
        af[s] = __builtin_bit_cast(f16x8, wp4[(size_t)s * 64]);

#pragma unroll
      for (int nt = 0; nt < 8; nt++) {
        const int bd = (((6 + (wv << 2) + (nt >> 1)) * LSTRIDE)
                       + (8 + ((nt & 1) << 4) + col)) << 2;
        f32x4 a = acc[g][nt];
#pragma unroll
        for (int s = 0; s < 7; s++) {
          uint4 tv = *(const uint4*)&xsb[bd + bofs[s] * (g + 1)];
          a = __builtin_amdgcn_mfma_f32_16x16x32_f16(
                af[s], __builtin_bit_cast(f16x8, tv), a, 0, 0, 0);
        }
        acc[g][nt] = a;
      }

      // write prefetched set g into the other buffer
      if (pf) {
        uint* db = xs + (cur ^ 1) * (CELLS * 4);
        int cd = (srow * LSTRIDE + (scg << 2)) << 2;
#pragma unroll
        for (int p = 0; p < 4; p++) {
          uint4 u;
          u.x = pack_f16x2(((const float*)&sr[0])[p], ((const float*)&sr[1])[p]);
          u.y = pack_f16x2(((const float*)&sr[2])[p], ((const float*)&sr[3])[p]);
          u.z = pack_f16x2(((const float*)&sr[4])[p], ((const float*)&sr[5])[p]);
          u.w = pack_f16x2(((const float*)&sr[6])[p], ((const float*)&sr[7])[p]);
          *(uint4*)&db[cd + 4 * p] = u;
        }
      }
    }
    __syncthreads();   // staging writes visible; all reads of cur done
    cur ^= 1;
  }

  // epilogue: D row (kg*4+r) = oc slot, col = pixel; fused st/sb binning.
#pragma unroll
  for (int nt = 0; nt < 8; nt++) {
    const int y = h0 + (wv << 2) + (nt >> 1);
    const int xx = w0 + ((nt & 1) << 4) + col;
    const size_t pix = (size_t)y * HW + xx;
    float stv = 0.f, sbv = 0.f;
#pragma unroll
    for (int g = 0; g < 3; g++) {
#pragma unroll
      for (int r = 0; r < 4; r++) {
        int slot = (kg << 2) + r;
        if (slot < 6) {
          int k18 = g * 6 + slot;
          float v = fmaxf(acc[g][nt][r] + swb[36 + k18], 0.f);
          out[(((size_t)(bz * 55 + 36 + k18)) << 18) + pix] = v;
          stv = fmaf(swb[k18], v, stv);
          sbv = fmaf(swb[18 + k18], v, sbv);
        }
      }
    }
    stv += __shfl_xor(stv, 16);
    stv += __shfl_xor(stv, 32);
    sbv += __shfl_xor(sbv, 16);
    sbv += __shfl_xor(sbv, 32);
    if (lane < 16) {
      int cell = row_seg[y] * 20 + col_seg[xx];
      atomicAdd(&bins[cell * 2], stv);
      atomicAdd(&bins[cell * 2 + 1], sbv);
    }
  }
  __syncthreads();
  for (int e = tid; e < 1200; e += 256) {
    float v = bins[e];
    if (v != 0.f) atomicAdd(&S[e], v);
  }
}

__global__ __launch_bounds__(1024) void finalize_kernel(
    const int* __restrict__ row_seg, const int* __restrict__ col_seg,
    const float* __restrict__ S, const float* __restrict__ btsum,
    const float* __restrict__ bb, float* __restrict__ tm,
    float* __restrict__ sbm, float* __restrict__ out)
{
  __shared__ int rowcnt[30], colcnt[20];
  const int t = threadIdx.x;
  if (t < 30) rowcnt[t] = 0;
  if (t >= 32 && t < 52) colcnt[t - 32] = 0;
  __syncthreads();
  if (t < 512) atomicAdd(&rowcnt[row_seg[t]], 1);
  else atomicAdd(&colcnt[col_seg[t - 512]], 1);
  __syncthreads();
  if (t < 600) {
    int r = t / 20, c = t - r * 20;
    float cnt = (float)(rowcnt[r] * colcnt[c]);
    float topm = S[2 * t] / (cnt * 144.f) + btsum[0] * (1.f / 36.f);
    float botm = S[2 * t + 1] / (cnt * 4.f) + bb[0];
    tm[t] = topm;
    float s = 1.f / (1.f + expf(-botm));
    sbm[t] = s;
#pragma unroll
    for (int b = 0; b < 4; b++) out[OUTX_SIZE + b * 600 + t] = s;
  }
}

__global__ __launch_bounds__(256) void fill_kernel(
    const int* __restrict__ row_seg, const int* __restrict__ col_seg,
    const float* __restrict__ tm, const float* __restrict__ sbm,
    float* __restrict__ out)
{
  const int idx = blockIdx.x * 256 + threadIdx.x;  // < 262144 (4 px / thread)
  const int b = idx >> 16;
  const int p4 = idx & 65535;
  const int h = p4 >> 7, w = (p4 & 127) << 2;
  const int rs = row_seg[h] * 20;
  float4 tmv, sbv;
  {
    int c0 = rs + col_seg[w + 0];
    int c1 = rs + col_seg[w + 1];
    int c2 = rs + col_seg[w + 2];
    int c3 = rs + col_seg[w + 3];
    tmv.x = tm[c0]; tmv.y = tm[c1]; tmv.z = tm[c2]; tmv.w = tm[c3];
    sbv.x = sbm[c0]; sbv.y = sbm[c1]; sbv.z = sbm[c2]; sbv.w = sbm[c3];
  }
  const size_t hw = (size_t)h * HW + w;
  float* base = out + (((size_t)(b * 55)) << 18) + hw;
#pragma unroll
  for (int ch = 0; ch < 36; ch++) *(float4*)(base + ((size_t)ch << 18)) = tmv;
  *(float4*)(base + ((size_t)54 << 18)) = sbv;
}

extern "C" void kernel_launch(void* const* d_in, const int* in_sizes, int n_in,
                              void* d_out, int out_size, void* d_ws, size_t ws_size,
                              hipStream_t stream) {
  const float* x       = (const float*)d_in[0];
  const int*   row_seg = (const int*)d_in[1];
  const int*   col_seg = (const int*)d_in[2];
  const float* w1 = (const float*)d_in[3];
  const float* b1 = (const float*)d_in[4];
  const float* w2 = (const float*)d_in[5];
  const float* b2 = (const float*)d_in[6];
  const float* w3 = (const float*)d_in[7];
  const float* b3 = (const float*)d_in[8];
  const float* wt = (const float*)d_in[9];
  const float* bt = (const float*)d_in[10];
  const float* wb = (const float*)d_in[11];
  const float* bb = (const float*)d_in[12];
  float* out = (float*)d_out;
  float* ws  = (float*)d_ws;

  prep_kernel<<<PREP_WBLK, 256, 0, stream>>>(w1, w2, w3, wt, bt, ws);

  dim3 g1(HW / BX, HW / BY, NB);
  conv_kernel<<<g1, 256, 0, stream>>>(x, (const uint*)(ws + WA_OFF),
                                      b1, b2, b3, row_seg, col_seg,
                                      ws + WSUM_OFF, wb, ws + S_OFF, out);

  finalize_kernel<<<1, 1024, 0, stream>>>(row_seg, col_seg, ws + S_OFF,
                                          ws + BTSUM_OFF, bb,
                                          ws + TM_OFF, ws + SBM_OFF, out);

  fill_kernel<<<NB * NPIX / 1024, 256, 0, stream>>>(row_seg, col_seg,
                                                    ws + TM_OFF, ws + SBM_OFF, out);
}